// Round 10
// baseline (366.585 us; speedup 1.0000x reference)
//
#include <hip/hip_runtime.h>
#include <hip/hip_fp16.h>

#define N_NODES 50000
#define N_EDGES 800000
#define NREL 32
#define NEG_SLOPE 0.2f
#define SCAN_NB ((N_NODES + 255) / 256)   // 196

// ---------------- CSR build ----------------
__global__ __launch_bounds__(256) void hist_kernel(const int* __restrict__ ei,
                                                   int* __restrict__ counts) {
    int e = blockIdx.x * 256 + threadIdx.x;
    if (e < N_EDGES) atomicAdd(&counts[ei[N_EDGES + e]], 1);
}

__global__ __launch_bounds__(256) void scan1_kernel(const int* __restrict__ counts,
                                                    int* __restrict__ offsets,
                                                    int* __restrict__ blocksums) {
    __shared__ int sh[256];
    int tid = threadIdx.x;
    int i = blockIdx.x * 256 + tid;
    int v = (i < N_NODES) ? counts[i] : 0;
    sh[tid] = v;
    __syncthreads();
    #pragma unroll
    for (int off = 1; off < 256; off <<= 1) {
        int t = (tid >= off) ? sh[tid - off] : 0;
        __syncthreads();
        sh[tid] += t;
        __syncthreads();
    }
    if (i < N_NODES) offsets[i] = sh[tid] - v;
    if (tid == 255) blocksums[blockIdx.x] = sh[255];
}

// blockIdx 0: scan the 196 block sums.  blockIdx 1..32: relation table row r.
__global__ __launch_bounds__(256) void scan2_rel_kernel(
    int* __restrict__ blocksums, int* __restrict__ blockoff,
    const float* __restrict__ rel_emb, const float* __restrict__ W_e,
    const float* __restrict__ att_edge, float* __restrict__ a_edge_r)
{
    int tid = threadIdx.x;
    if (blockIdx.x == 0) {
        __shared__ int sh[256];
        int v = (tid < SCAN_NB) ? blocksums[tid] : 0;
        sh[tid] = v;
        __syncthreads();
        #pragma unroll
        for (int off = 1; off < 256; off <<= 1) {
            int t = (tid >= off) ? sh[tid - off] : 0;
            __syncthreads();
            sh[tid] += t;
            __syncthreads();
        }
        if (tid < SCAN_NB) blockoff[tid] = sh[tid] - v;
    } else if (tid < 64) {
        int r = blockIdx.x - 1;
        int h = tid >> 4;
        int i16 = tid & 15;
        float rr = rel_emb[r * 64 + tid];
        float4 acc = {0.f, 0.f, 0.f, 0.f};
        #pragma unroll
        for (int k = 0; k < 64; ++k) {
            float rv = __shfl(rr, k);
            float4 wv = *(const float4*)(W_e + k * 256 + h * 64 + i16 * 4);
            acc.x += rv * wv.x; acc.y += rv * wv.y;
            acc.z += rv * wv.z; acc.w += rv * wv.w;
        }
        float4 aev = *(const float4*)(att_edge + h * 64 + i16 * 4);
        float ae = acc.x * aev.x + acc.y * aev.y + acc.z * aev.z + acc.w * aev.w;
        #pragma unroll
        for (int m = 8; m >= 1; m >>= 1) ae += __shfl_xor(ae, m);
        if (i16 == 0) a_edge_r[r * 4 + h] = ae;
    }
}

__global__ __launch_bounds__(256) void scan3_kernel(int* __restrict__ offsets,
                                                    const int* __restrict__ blockoff,
                                                    int* __restrict__ cursor) {
    int i = blockIdx.x * 256 + threadIdx.x;
    if (i < N_NODES) {
        int o = offsets[i] + blockoff[blockIdx.x];
        offsets[i] = o;
        cursor[i] = o;
    }
}

// ---------------- node transform: xh = x@W (fp16, [N][C][H] layout), a_src, a_dst ----------------
// W staged once per block into LDS. Lane owns 4 cols. 4 nodes per wave-iteration.
__global__ __launch_bounds__(256, 2) void node_xform(
    const float* __restrict__ x, const float* __restrict__ W,
    const float* __restrict__ att_src, const float* __restrict__ att_dst,
    __half* __restrict__ xh, float* __restrict__ a_src, float* __restrict__ a_dst)
{
    __shared__ float4 Wl[64][64];   // [k][c4], 64 KB
    int tid = threadIdx.x;
    int lane = tid & 63;
    int wv = tid >> 6;

    {
        const float4* Wg = (const float4*)W;
        float4* Wf = &Wl[0][0];
        #pragma unroll
        for (int j = 0; j < 16; ++j) Wf[tid + 256 * j] = Wg[tid + 256 * j];
    }
    __syncthreads();

    int c4 = lane;
    int h = lane >> 4;
    float4 asv = ((const float4*)att_src)[c4];
    float4 adv = ((const float4*)att_dst)[c4];

    for (int base = blockIdx.x * 16 + wv * 4; base < N_NODES; base += gridDim.x * 16) {
        const float* __restrict__ xr = x + (size_t)base * 64;
        float4 A0 = {0,0,0,0}, A1 = {0,0,0,0}, A2 = {0,0,0,0}, A3 = {0,0,0,0};
        #pragma unroll 8
        for (int k = 0; k < 64; ++k) {
            float4 wv4 = Wl[k][c4];
            float x0 = xr[k], x1 = xr[64 + k], x2 = xr[128 + k], x3 = xr[192 + k];
            A0.x = fmaf(x0, wv4.x, A0.x); A0.y = fmaf(x0, wv4.y, A0.y);
            A0.z = fmaf(x0, wv4.z, A0.z); A0.w = fmaf(x0, wv4.w, A0.w);
            A1.x = fmaf(x1, wv4.x, A1.x); A1.y = fmaf(x1, wv4.y, A1.y);
            A1.z = fmaf(x1, wv4.z, A1.z); A1.w = fmaf(x1, wv4.w, A1.w);
            A2.x = fmaf(x2, wv4.x, A2.x); A2.y = fmaf(x2, wv4.y, A2.y);
            A2.z = fmaf(x2, wv4.z, A2.z); A2.w = fmaf(x2, wv4.w, A2.w);
            A3.x = fmaf(x3, wv4.x, A3.x); A3.y = fmaf(x3, wv4.y, A3.y);
            A3.z = fmaf(x3, wv4.z, A3.z); A3.w = fmaf(x3, wv4.w, A3.w);
        }

        int cwb = (lane & 15) * 4;
        {
            size_t b = (size_t)(base + 0) * 256 + cwb * 4 + h;
            xh[b] = __float2half(A0.x); xh[b + 4] = __float2half(A0.y);
            xh[b + 8] = __float2half(A0.z); xh[b + 12] = __float2half(A0.w);
            b += 256;
            xh[b] = __float2half(A1.x); xh[b + 4] = __float2half(A1.y);
            xh[b + 8] = __float2half(A1.z); xh[b + 12] = __float2half(A1.w);
            b += 256;
            xh[b] = __float2half(A2.x); xh[b + 4] = __float2half(A2.y);
            xh[b + 8] = __float2half(A2.z); xh[b + 12] = __float2half(A2.w);
            b += 256;
            xh[b] = __float2half(A3.x); xh[b + 4] = __float2half(A3.y);
            xh[b + 8] = __float2half(A3.z); xh[b + 12] = __float2half(A3.w);
        }

        float s0 = A0.x*asv.x + A0.y*asv.y + A0.z*asv.z + A0.w*asv.w;
        float d0 = A0.x*adv.x + A0.y*adv.y + A0.z*adv.z + A0.w*adv.w;
        float s1 = A1.x*asv.x + A1.y*asv.y + A1.z*asv.z + A1.w*asv.w;
        float d1 = A1.x*adv.x + A1.y*adv.y + A1.z*adv.z + A1.w*adv.w;
        float s2 = A2.x*asv.x + A2.y*asv.y + A2.z*asv.z + A2.w*asv.w;
        float d2 = A2.x*adv.x + A2.y*adv.y + A2.z*adv.z + A2.w*adv.w;
        float s3 = A3.x*asv.x + A3.y*asv.y + A3.z*asv.z + A3.w*asv.w;
        float d3 = A3.x*adv.x + A3.y*adv.y + A3.z*adv.z + A3.w*adv.w;
        #pragma unroll
        for (int m = 1; m <= 8; m <<= 1) {
            s0 += __shfl_xor(s0, m); d0 += __shfl_xor(d0, m);
            s1 += __shfl_xor(s1, m); d1 += __shfl_xor(d1, m);
            s2 += __shfl_xor(s2, m); d2 += __shfl_xor(d2, m);
            s3 += __shfl_xor(s3, m); d3 += __shfl_xor(d3, m);
        }
        if ((lane & 15) == 0) {
            a_src[(base + 0) * 4 + h] = s0; a_dst[(base + 0) * 4 + h] = d0;
            a_src[(base + 1) * 4 + h] = s1; a_dst[(base + 1) * 4 + h] = d1;
            a_src[(base + 2) * 4 + h] = s2; a_dst[(base + 2) * 4 + h] = d2;
            a_src[(base + 3) * 4 + h] = s3; a_dst[(base + 3) * 4 + h] = d3;
        }
    }
}

// ---------------- scatter + exp: dense per-edge alpha/exp, denom atomics ----------------
// One lane per edge (full utilization). Writes {ushort src, half4 ev} to the dst bucket.
__global__ __launch_bounds__(256) void scatter_ex(
    const int* __restrict__ ei, const int* __restrict__ etype,
    const float* __restrict__ a_src, const float* __restrict__ a_dst,
    const float* __restrict__ a_edge_r, int* __restrict__ cursor,
    float* __restrict__ denom, unsigned short* __restrict__ el_src,
    uint2* __restrict__ el_ex)
{
    int e = blockIdx.x * 256 + threadIdx.x;
    if (e >= N_EDGES) return;
    int s = ei[e];
    int d = ei[N_EDGES + e];
    int t = etype[e];
    float4 as = ((const float4*)a_src)[s];
    float4 ad = ((const float4*)a_dst)[d];
    float4 ae = ((const float4*)a_edge_r)[t];

    float b0 = as.x + ad.x + ae.x; b0 = b0 > 0.f ? b0 : NEG_SLOPE * b0;
    float b1 = as.y + ad.y + ae.y; b1 = b1 > 0.f ? b1 : NEG_SLOPE * b1;
    float b2 = as.z + ad.z + ae.z; b2 = b2 > 0.f ? b2 : NEG_SLOPE * b2;
    float b3 = as.w + ad.w + ae.w; b3 = b3 > 0.f ? b3 : NEG_SLOPE * b3;
    float e0 = __expf(b0), e1 = __expf(b1), e2 = __expf(b2), e3 = __expf(b3);

    atomicAdd(&denom[d * 4 + 0], e0);
    atomicAdd(&denom[d * 4 + 1], e1);
    atomicAdd(&denom[d * 4 + 2], e2);
    atomicAdd(&denom[d * 4 + 3], e3);

    __half2 lo = __floats2half2_rn(e0, e1);
    __half2 hi = __floats2half2_rn(e2, e3);
    uint2 pk;
    pk.x = *(unsigned int*)&lo;
    pk.y = *(unsigned int*)&hi;

    int pos = atomicAdd(&cursor[d], 1);
    el_src[pos] = (unsigned short)s;
    el_ex[pos] = pk;
}

// ---------------- aggregate (2 waves per dst node, exp precomputed) ----------------
__global__ __launch_bounds__(256) void aggregate(
    const int* __restrict__ offsets, const int* __restrict__ counts,
    const unsigned short* __restrict__ el_src, const uint2* __restrict__ el_ex,
    const float* __restrict__ denom, const __half* __restrict__ xh,
    const float* __restrict__ bias, float* __restrict__ out)
{
    __shared__ uint2  exsh[4][64];
    __shared__ int    ssh[4][64];
    __shared__ float4 pnum[4][64];

    int lane = threadIdx.x & 63;
    int warp = threadIdx.x >> 6;   // 0..3
    int pair = warp >> 1;
    int half = warp & 1;
    int d = blockIdx.x * 2 + pair;

    int beg = offsets[d];
    int deg = counts[d];
    int h1 = (deg + 1) >> 1;
    int mybeg = beg + (half ? h1 : 0);
    int mydeg = half ? (deg - h1) : h1;

    float n0 = 0.f, n1 = 0.f, n2 = 0.f, n3 = 0.f;

    for (int base = 0; base < mydeg; base += 64) {
        int m = mydeg - base; if (m > 64) m = 64;

        uint2 pk = make_uint2(0u, 0u);
        int s = 0;
        if (lane < m) {
            int idx = mybeg + base + lane;
            pk = el_ex[idx];
            s = el_src[idx];
        }
        exsh[warp][lane] = pk;   // wave-private rows; wave-synchronous RAW
        ssh[warp][lane]  = s;

        #pragma unroll 4
        for (int j = 0; j < m; ++j) {
            uint2 e2 = exsh[warp][j];
            int sj = ssh[warp][j];
            __half2 lo = *(__half2*)&e2.x;
            __half2 hi = *(__half2*)&e2.y;
            float2 w01 = __half22float2(lo);
            float2 w23 = __half22float2(hi);
            const __half2* __restrict__ xr =
                (const __half2*)(xh + (size_t)sj * 256 + lane * 4);
            __half2 p0 = xr[0], p1 = xr[1];
            float2 f0 = __half22float2(p0), f1 = __half22float2(p1);
            n0 = fmaf(w01.x, f0.x, n0);
            n1 = fmaf(w01.y, f0.y, n1);
            n2 = fmaf(w23.x, f1.x, n2);
            n3 = fmaf(w23.y, f1.y, n3);
        }
    }

    pnum[warp][lane] = make_float4(n0, n1, n2, n3);
    __syncthreads();

    if (half == 0) {
        float4 on = pnum[warp + 1][lane];
        n0 += on.x; n1 += on.y; n2 += on.z; n3 += on.w;

        float r = 0.f;
        if (deg > 0) {
            float4 dn = ((const float4*)denom)[d];
            r = 0.25f * (n0 / dn.x + n1 / dn.y + n2 / dn.z + n3 / dn.w);
        }
        out[(size_t)d * 64 + lane] = r + bias[lane];
    }
}

extern "C" void kernel_launch(void* const* d_in, const int* in_sizes, int n_in,
                              void* d_out, int out_size, void* d_ws, size_t ws_size,
                              hipStream_t stream) {
    const float* x        = (const float*)d_in[0];
    const int*   ei       = (const int*)  d_in[1];
    const int*   etype    = (const int*)  d_in[2];
    const float* rel_emb  = (const float*)d_in[3];
    const float* W        = (const float*)d_in[4];
    const float* W_e      = (const float*)d_in[5];
    const float* att_src  = (const float*)d_in[6];
    const float* att_dst  = (const float*)d_in[7];
    const float* att_edge = (const float*)d_in[8];
    const float* bias     = (const float*)d_in[9];
    float* out = (float*)d_out;

    // workspace layout (counts+denom contiguous for a single memset)
    char* ws = (char*)d_ws;
    __half* xh      = (__half*)ws;                              // 25.6 MB
    char* p = ws + (size_t)N_NODES * 256 * 2;
    int*   counts   = (int*)p;                p += N_NODES * 4;        // zeroed
    float* denom    = (float*)p;              p += N_NODES * 4 * 4;    // zeroed
    float* a_src    = (float*)p;              p += N_NODES * 4 * 4;
    float* a_dst    = (float*)p;              p += N_NODES * 4 * 4;
    float* a_edge_r = (float*)p;              p += NREL * 4 * 4;
    int*   offsets  = (int*)p;                p += N_NODES * 4;
    int*   cursor   = (int*)p;                p += N_NODES * 4;
    int*   blocksums= (int*)p;                p += 256 * 4;
    int*   blockoff = (int*)p;                p += 256 * 4;
    unsigned short* el_src = (unsigned short*)p;  p += (size_t)N_EDGES * 2;
    uint2* el_ex    = (uint2*)p;              p += (size_t)N_EDGES * 8;

    hipMemsetAsync(counts, 0, N_NODES * sizeof(int) * 5, stream);  // counts + denom
    hist_kernel<<<(N_EDGES + 255) / 256, 256, 0, stream>>>(ei, counts);
    scan1_kernel<<<SCAN_NB, 256, 0, stream>>>(counts, offsets, blocksums);
    scan2_rel_kernel<<<1 + NREL, 256, 0, stream>>>(blocksums, blockoff,
                                                   rel_emb, W_e, att_edge, a_edge_r);
    scan3_kernel<<<SCAN_NB, 256, 0, stream>>>(offsets, blockoff, cursor);
    node_xform<<<512, 256, 0, stream>>>(x, W, att_src, att_dst, xh, a_src, a_dst);
    scatter_ex<<<(N_EDGES + 255) / 256, 256, 0, stream>>>(ei, etype, a_src, a_dst,
                                                          a_edge_r, cursor, denom,
                                                          el_src, el_ex);
    aggregate<<<N_NODES / 2, 256, 0, stream>>>(offsets, counts, el_src, el_ex,
                                               denom, xh, bias, out);
}

// Round 11
// 232.164 us; speedup vs baseline: 1.5790x; 1.5790x over previous
//
#include <hip/hip_runtime.h>
#include <hip/hip_fp16.h>

#define N_NODES 50000
#define N_EDGES 800000
#define NREL 32
#define NEG_SLOPE 0.2f
#define SCAN_NB ((N_NODES + 255) / 256)   // 196
#define NX_GRID 512
#define HIST_NB ((N_EDGES + 255) / 256)   // 3125

// ---------------- fused: node_xform (blocks 0..511) ∥ hist (blocks 512..) ----------------
__global__ __launch_bounds__(256, 2) void fused_nx_hist(
    const float* __restrict__ x, const float* __restrict__ W,
    const float* __restrict__ att_src, const float* __restrict__ att_dst,
    __half* __restrict__ xh, float* __restrict__ a_src, float* __restrict__ a_dst,
    const int* __restrict__ ei, int* __restrict__ counts)
{
    __shared__ float4 Wl[64][64];   // 64 KB (allocated for all blocks)
    int tid = threadIdx.x;

    if (blockIdx.x >= NX_GRID) {
        // ---- histogram part ----
        int e = (blockIdx.x - NX_GRID) * 256 + tid;
        if (e < N_EDGES) atomicAdd(&counts[ei[N_EDGES + e]], 1);
        return;
    }

    // ---- node transform part ----
    int lane = tid & 63;
    int wv = tid >> 6;
    {
        const float4* Wg = (const float4*)W;
        float4* Wf = &Wl[0][0];
        #pragma unroll
        for (int j = 0; j < 16; ++j) Wf[tid + 256 * j] = Wg[tid + 256 * j];
    }
    __syncthreads();

    int c4 = lane;
    int h = lane >> 4;
    float4 asv = ((const float4*)att_src)[c4];
    float4 adv = ((const float4*)att_dst)[c4];

    for (int base = blockIdx.x * 16 + wv * 4; base < N_NODES; base += NX_GRID * 16) {
        const float* __restrict__ xr = x + (size_t)base * 64;
        float4 A0 = {0,0,0,0}, A1 = {0,0,0,0}, A2 = {0,0,0,0}, A3 = {0,0,0,0};
        #pragma unroll 8
        for (int k = 0; k < 64; ++k) {
            float4 wv4 = Wl[k][c4];
            float x0 = xr[k], x1 = xr[64 + k], x2 = xr[128 + k], x3 = xr[192 + k];
            A0.x = fmaf(x0, wv4.x, A0.x); A0.y = fmaf(x0, wv4.y, A0.y);
            A0.z = fmaf(x0, wv4.z, A0.z); A0.w = fmaf(x0, wv4.w, A0.w);
            A1.x = fmaf(x1, wv4.x, A1.x); A1.y = fmaf(x1, wv4.y, A1.y);
            A1.z = fmaf(x1, wv4.z, A1.z); A1.w = fmaf(x1, wv4.w, A1.w);
            A2.x = fmaf(x2, wv4.x, A2.x); A2.y = fmaf(x2, wv4.y, A2.y);
            A2.z = fmaf(x2, wv4.z, A2.z); A2.w = fmaf(x2, wv4.w, A2.w);
            A3.x = fmaf(x3, wv4.x, A3.x); A3.y = fmaf(x3, wv4.y, A3.y);
            A3.z = fmaf(x3, wv4.z, A3.z); A3.w = fmaf(x3, wv4.w, A3.w);
        }

        int cwb = (lane & 15) * 4;
        {
            size_t b = (size_t)(base + 0) * 256 + cwb * 4 + h;
            xh[b] = __float2half(A0.x); xh[b + 4] = __float2half(A0.y);
            xh[b + 8] = __float2half(A0.z); xh[b + 12] = __float2half(A0.w);
            b += 256;
            xh[b] = __float2half(A1.x); xh[b + 4] = __float2half(A1.y);
            xh[b + 8] = __float2half(A1.z); xh[b + 12] = __float2half(A1.w);
            b += 256;
            xh[b] = __float2half(A2.x); xh[b + 4] = __float2half(A2.y);
            xh[b + 8] = __float2half(A2.z); xh[b + 12] = __float2half(A2.w);
            b += 256;
            xh[b] = __float2half(A3.x); xh[b + 4] = __float2half(A3.y);
            xh[b + 8] = __float2half(A3.z); xh[b + 12] = __float2half(A3.w);
        }

        float s0 = A0.x*asv.x + A0.y*asv.y + A0.z*asv.z + A0.w*asv.w;
        float d0 = A0.x*adv.x + A0.y*adv.y + A0.z*adv.z + A0.w*adv.w;
        float s1 = A1.x*asv.x + A1.y*asv.y + A1.z*asv.z + A1.w*asv.w;
        float d1 = A1.x*adv.x + A1.y*adv.y + A1.z*adv.z + A1.w*adv.w;
        float s2 = A2.x*asv.x + A2.y*asv.y + A2.z*asv.z + A2.w*asv.w;
        float d2 = A2.x*adv.x + A2.y*adv.y + A2.z*adv.z + A2.w*adv.w;
        float s3 = A3.x*asv.x + A3.y*asv.y + A3.z*asv.z + A3.w*asv.w;
        float d3 = A3.x*adv.x + A3.y*adv.y + A3.z*adv.z + A3.w*adv.w;
        #pragma unroll
        for (int m = 1; m <= 8; m <<= 1) {
            s0 += __shfl_xor(s0, m); d0 += __shfl_xor(d0, m);
            s1 += __shfl_xor(s1, m); d1 += __shfl_xor(d1, m);
            s2 += __shfl_xor(s2, m); d2 += __shfl_xor(d2, m);
            s3 += __shfl_xor(s3, m); d3 += __shfl_xor(d3, m);
        }
        if ((lane & 15) == 0) {
            a_src[(base + 0) * 4 + h] = s0; a_dst[(base + 0) * 4 + h] = d0;
            a_src[(base + 1) * 4 + h] = s1; a_dst[(base + 1) * 4 + h] = d1;
            a_src[(base + 2) * 4 + h] = s2; a_dst[(base + 2) * 4 + h] = d2;
            a_src[(base + 3) * 4 + h] = s3; a_dst[(base + 3) * 4 + h] = d3;
        }
    }
}

// ---------------- scans ----------------
__global__ __launch_bounds__(256) void scan1_kernel(const int* __restrict__ counts,
                                                    int* __restrict__ offsets,
                                                    int* __restrict__ blocksums) {
    __shared__ int sh[256];
    int tid = threadIdx.x;
    int i = blockIdx.x * 256 + tid;
    int v = (i < N_NODES) ? counts[i] : 0;
    sh[tid] = v;
    __syncthreads();
    #pragma unroll
    for (int off = 1; off < 256; off <<= 1) {
        int t = (tid >= off) ? sh[tid - off] : 0;
        __syncthreads();
        sh[tid] += t;
        __syncthreads();
    }
    if (i < N_NODES) offsets[i] = sh[tid] - v;
    if (tid == 255) blocksums[blockIdx.x] = sh[255];
}

// blockIdx 0: scan block sums.  blockIdx 1..32: relation table row r.
__global__ __launch_bounds__(256) void scan2_rel_kernel(
    int* __restrict__ blocksums, int* __restrict__ blockoff,
    const float* __restrict__ rel_emb, const float* __restrict__ W_e,
    const float* __restrict__ att_edge, float* __restrict__ a_edge_r)
{
    int tid = threadIdx.x;
    if (blockIdx.x == 0) {
        __shared__ int sh[256];
        int v = (tid < SCAN_NB) ? blocksums[tid] : 0;
        sh[tid] = v;
        __syncthreads();
        #pragma unroll
        for (int off = 1; off < 256; off <<= 1) {
            int t = (tid >= off) ? sh[tid - off] : 0;
            __syncthreads();
            sh[tid] += t;
            __syncthreads();
        }
        if (tid < SCAN_NB) blockoff[tid] = sh[tid] - v;
    } else if (tid < 64) {
        int r = blockIdx.x - 1;
        int h = tid >> 4;
        int i16 = tid & 15;
        float rr = rel_emb[r * 64 + tid];
        float4 acc = {0.f, 0.f, 0.f, 0.f};
        #pragma unroll
        for (int k = 0; k < 64; ++k) {
            float rv = __shfl(rr, k);
            float4 wv = *(const float4*)(W_e + k * 256 + h * 64 + i16 * 4);
            acc.x += rv * wv.x; acc.y += rv * wv.y;
            acc.z += rv * wv.z; acc.w += rv * wv.w;
        }
        float4 aev = *(const float4*)(att_edge + h * 64 + i16 * 4);
        float ae = acc.x * aev.x + acc.y * aev.y + acc.z * aev.z + acc.w * aev.w;
        #pragma unroll
        for (int m = 8; m >= 1; m >>= 1) ae += __shfl_xor(ae, m);
        if (i16 == 0) a_edge_r[r * 4 + h] = ae;
    }
}

__global__ __launch_bounds__(256) void scan3_kernel(int* __restrict__ offsets,
                                                    const int* __restrict__ blockoff,
                                                    int* __restrict__ cursor) {
    int i = blockIdx.x * 256 + threadIdx.x;
    if (i < N_NODES) {
        int o = offsets[i] + blockoff[blockIdx.x];
        offsets[i] = o;
        cursor[i] = o;
    }
}

// ---------------- fused: edge_ex (blocks 0..3124) ∥ scatter (blocks 3125..) ----------------
// edge_ex: dense per-edge alpha/exp -> ex4[e] (8B coalesced). No atomics.
// scatter: elist[pos] = edge id (4B scatter, L2-merged).
__global__ __launch_bounds__(256) void fused_ex_scatter(
    const int* __restrict__ ei, const int* __restrict__ etype,
    const float* __restrict__ a_src, const float* __restrict__ a_dst,
    const float* __restrict__ a_edge_r, int* __restrict__ cursor,
    uint2* __restrict__ ex4, int* __restrict__ elist)
{
    int tid = threadIdx.x;
    if (blockIdx.x < HIST_NB) {
        int e = blockIdx.x * 256 + tid;
        if (e >= N_EDGES) return;
        int s = ei[e];
        int d = ei[N_EDGES + e];
        int t = etype[e];
        float4 as = ((const float4*)a_src)[s];
        float4 ad = ((const float4*)a_dst)[d];
        float4 ae = ((const float4*)a_edge_r)[t];

        float b0 = as.x + ad.x + ae.x; b0 = b0 > 0.f ? b0 : NEG_SLOPE * b0;
        float b1 = as.y + ad.y + ae.y; b1 = b1 > 0.f ? b1 : NEG_SLOPE * b1;
        float b2 = as.z + ad.z + ae.z; b2 = b2 > 0.f ? b2 : NEG_SLOPE * b2;
        float b3 = as.w + ad.w + ae.w; b3 = b3 > 0.f ? b3 : NEG_SLOPE * b3;

        __half2 lo = __floats2half2_rn(__expf(b0), __expf(b1));
        __half2 hi = __floats2half2_rn(__expf(b2), __expf(b3));
        uint2 pk;
        pk.x = *(unsigned int*)&lo;
        pk.y = *(unsigned int*)&hi;
        ex4[e] = pk;
    } else {
        int e = (blockIdx.x - HIST_NB) * 256 + tid;
        if (e >= N_EDGES) return;
        int d = ei[N_EDGES + e];
        int pos = atomicAdd(&cursor[d], 1);
        elist[pos] = e;
    }
}

// ---------------- aggregate (2 waves per dst node) ----------------
// Phase A: lane loads its edge id, gathers src + ev from dense L2-resident arrays.
// Phase B: LDS broadcast + xh gather + FMA. Denominator: per-lane sums ->
// LDS merge across wave pair -> butterfly.
__global__ __launch_bounds__(256) void aggregate(
    const int* __restrict__ offsets, const int* __restrict__ counts,
    const int* __restrict__ elist, const int* __restrict__ ei,
    const uint2* __restrict__ ex4, const __half* __restrict__ xh,
    const float* __restrict__ bias, float* __restrict__ out)
{
    __shared__ uint2  exsh[4][64];
    __shared__ int    ssh[4][64];
    __shared__ float4 pnum[4][64];
    __shared__ float4 pden[4][64];

    int lane = threadIdx.x & 63;
    int warp = threadIdx.x >> 6;   // 0..3
    int pair = warp >> 1;
    int half = warp & 1;
    int d = blockIdx.x * 2 + pair;

    int beg = offsets[d];
    int deg = counts[d];
    int h1 = (deg + 1) >> 1;
    int mybeg = beg + (half ? h1 : 0);
    int mydeg = half ? (deg - h1) : h1;

    float n0 = 0.f, n1 = 0.f, n2 = 0.f, n3 = 0.f;
    float d0 = 0.f, d1 = 0.f, d2 = 0.f, d3 = 0.f;

    for (int base = 0; base < mydeg; base += 64) {
        int m = mydeg - base; if (m > 64) m = 64;

        uint2 pk = make_uint2(0u, 0u);
        int s = 0;
        if (lane < m) {
            int eid = elist[mybeg + base + lane];
            s = ei[eid];
            pk = ex4[eid];
        }
        {   // accumulate denominator partials from my lane's edge
            __half2 lo = *(__half2*)&pk.x;
            __half2 hi = *(__half2*)&pk.y;
            float2 w01 = __half22float2(lo);
            float2 w23 = __half22float2(hi);
            d0 += w01.x; d1 += w01.y; d2 += w23.x; d3 += w23.y;
        }
        exsh[warp][lane] = pk;   // wave-private rows; wave-synchronous RAW
        ssh[warp][lane]  = s;

        #pragma unroll 4
        for (int j = 0; j < m; ++j) {
            uint2 e2 = exsh[warp][j];
            int sj = ssh[warp][j];
            __half2 lo = *(__half2*)&e2.x;
            __half2 hi = *(__half2*)&e2.y;
            float2 w01 = __half22float2(lo);
            float2 w23 = __half22float2(hi);
            const __half2* __restrict__ xr =
                (const __half2*)(xh + (size_t)sj * 256 + lane * 4);
            __half2 p0 = xr[0], p1 = xr[1];
            float2 f0 = __half22float2(p0), f1 = __half22float2(p1);
            n0 = fmaf(w01.x, f0.x, n0);
            n1 = fmaf(w01.y, f0.y, n1);
            n2 = fmaf(w23.x, f1.x, n2);
            n3 = fmaf(w23.y, f1.y, n3);
        }
    }

    pnum[warp][lane] = make_float4(n0, n1, n2, n3);
    pden[warp][lane] = make_float4(d0, d1, d2, d3);
    __syncthreads();

    if (half == 0) {
        float4 on = pnum[warp + 1][lane];
        float4 od = pden[warp + 1][lane];
        n0 += on.x; n1 += on.y; n2 += on.z; n3 += on.w;
        d0 += od.x; d1 += od.y; d2 += od.z; d3 += od.w;

        #pragma unroll
        for (int msk = 32; msk >= 1; msk >>= 1) {
            d0 += __shfl_xor(d0, msk);
            d1 += __shfl_xor(d1, msk);
            d2 += __shfl_xor(d2, msk);
            d3 += __shfl_xor(d3, msk);
        }

        float r = 0.f;
        if (deg > 0)
            r = 0.25f * (n0 / d0 + n1 / d1 + n2 / d2 + n3 / d3);
        out[(size_t)d * 64 + lane] = r + bias[lane];
    }
}

extern "C" void kernel_launch(void* const* d_in, const int* in_sizes, int n_in,
                              void* d_out, int out_size, void* d_ws, size_t ws_size,
                              hipStream_t stream) {
    const float* x        = (const float*)d_in[0];
    const int*   ei       = (const int*)  d_in[1];
    const int*   etype    = (const int*)  d_in[2];
    const float* rel_emb  = (const float*)d_in[3];
    const float* W        = (const float*)d_in[4];
    const float* W_e      = (const float*)d_in[5];
    const float* att_src  = (const float*)d_in[6];
    const float* att_dst  = (const float*)d_in[7];
    const float* att_edge = (const float*)d_in[8];
    const float* bias     = (const float*)d_in[9];
    float* out = (float*)d_out;

    char* ws = (char*)d_ws;
    __half* xh      = (__half*)ws;                              // 25.6 MB
    char* p = ws + (size_t)N_NODES * 256 * 2;
    int*   counts   = (int*)p;                p += N_NODES * 4;   // zeroed
    float* a_src    = (float*)p;              p += N_NODES * 4 * 4;
    float* a_dst    = (float*)p;              p += N_NODES * 4 * 4;
    float* a_edge_r = (float*)p;              p += NREL * 4 * 4;
    int*   offsets  = (int*)p;                p += N_NODES * 4;
    int*   cursor   = (int*)p;                p += N_NODES * 4;
    int*   blocksums= (int*)p;                p += 256 * 4;
    int*   blockoff = (int*)p;                p += 256 * 4;
    int*   elist    = (int*)p;                p += (size_t)N_EDGES * 4;
    uint2* ex4      = (uint2*)p;              p += (size_t)N_EDGES * 8;

    hipMemsetAsync(counts, 0, N_NODES * sizeof(int), stream);
    fused_nx_hist<<<NX_GRID + HIST_NB, 256, 0, stream>>>(x, W, att_src, att_dst,
                                                         xh, a_src, a_dst, ei, counts);
    scan1_kernel<<<SCAN_NB, 256, 0, stream>>>(counts, offsets, blocksums);
    scan2_rel_kernel<<<1 + NREL, 256, 0, stream>>>(blocksums, blockoff,
                                                   rel_emb, W_e, att_edge, a_edge_r);
    scan3_kernel<<<SCAN_NB, 256, 0, stream>>>(offsets, blockoff, cursor);
    fused_ex_scatter<<<2 * HIST_NB, 256, 0, stream>>>(ei, etype, a_src, a_dst,
                                                      a_edge_r, cursor, ex4, elist);
    aggregate<<<N_NODES / 2, 256, 0, stream>>>(offsets, counts, elist, ei,
                                               ex4, xh, bias, out);
}

// Round 12
// 207.585 us; speedup vs baseline: 1.7659x; 1.1184x over previous
//
#include <hip/hip_runtime.h>
#include <hip/hip_fp16.h>

#define N_NODES 50000
#define N_EDGES 800000
#define NREL 32
#define NEG_SLOPE 0.2f
#define SCAN_NB ((N_NODES + 255) / 256)   // 196
#define HIST_NB ((N_EDGES + 255) / 256)   // 3125
#define NXB 256                           // nx_mfma grid
#define NTILES (N_NODES / 16)             // 3125 wave tiles (exact)

typedef _Float16 f16x8 __attribute__((ext_vector_type(8)));
typedef float f32x4 __attribute__((ext_vector_type(4)));

// ---------------- prep: relation table (blocks 0..31) + vsd (blocks 32..39) ----------------
// vsd[col8][k] = sum_c W[k][h*64+c] * att[h*64+c], col8 = 2h + (0=src,1=dst)
__global__ __launch_bounds__(64) void prep_kernel(
    const float* __restrict__ rel_emb, const float* __restrict__ W_e,
    const float* __restrict__ att_edge, float* __restrict__ a_edge_r,
    const float* __restrict__ W, const float* __restrict__ att_src,
    const float* __restrict__ att_dst, float* __restrict__ vsd)
{
    int tid = threadIdx.x;
    if (blockIdx.x < NREL) {
        int r = blockIdx.x;
        int h = tid >> 4;
        int i16 = tid & 15;
        float rr = rel_emb[r * 64 + tid];
        float4 acc = {0.f, 0.f, 0.f, 0.f};
        #pragma unroll
        for (int k = 0; k < 64; ++k) {
            float rv = __shfl(rr, k);
            float4 wv = *(const float4*)(W_e + k * 256 + h * 64 + i16 * 4);
            acc.x += rv * wv.x; acc.y += rv * wv.y;
            acc.z += rv * wv.z; acc.w += rv * wv.w;
        }
        float4 aev = *(const float4*)(att_edge + h * 64 + i16 * 4);
        float ae = acc.x * aev.x + acc.y * aev.y + acc.z * aev.z + acc.w * aev.w;
        #pragma unroll
        for (int m = 8; m >= 1; m >>= 1) ae += __shfl_xor(ae, m);
        if (i16 == 0) a_edge_r[r * 4 + h] = ae;
    } else {
        int col8 = blockIdx.x - NREL;   // 0..7
        int h = col8 >> 1;
        const float* att = (col8 & 1) ? att_dst : att_src;
        int k = tid;                    // 0..63
        float s = 0.f;
        #pragma unroll 8
        for (int c = 0; c < 64; ++c)
            s += W[k * 256 + h * 64 + c] * att[h * 64 + c];
        vsd[col8 * 64 + k] = s;
    }
}

// ---------------- node transform via MFMA ----------------
// Wave tile = 16 nodes. A = x rows (fp16), B = W fp16 staged in LDS [col][k].
// Cols 0..255 = W; cols 256..263 = vsd (a_src/a_dst as extra GEMM outputs).
// D layout (m89): col = lane&15, row(node) = (lane>>4)*4 + reg.
__global__ __launch_bounds__(256) void nx_mfma(
    const float* __restrict__ x, const float* __restrict__ W,
    const float* __restrict__ vsd, __half* __restrict__ xh,
    float* __restrict__ a_src, float* __restrict__ a_dst)
{
    __shared__ __align__(16) _Float16 Wl[272][72];
    int tid = threadIdx.x;

    // stage W -> Wl[col][k] (fp16)
    for (int idx = tid; idx < 64 * 256; idx += 256) {
        int k = idx >> 8, col = idx & 255;
        Wl[col][k] = (_Float16)W[idx];
    }
    for (int idx = tid; idx < 64 * 16; idx += 256) {
        int k = idx >> 4, col8 = idx & 15;
        Wl[256 + col8][k] = (_Float16)((col8 < 8) ? vsd[col8 * 64 + k] : 0.f);
    }
    __syncthreads();

    int lane = tid & 63;
    int wv = tid >> 6;
    int r16 = lane & 15;    // A row / D col
    int kg = lane >> 4;     // k group

    for (int tile = blockIdx.x * 4 + wv; tile < NTILES; tile += NXB * 4) {
        int nb = tile * 16;
        const float* __restrict__ xrow = x + (size_t)(nb + r16) * 64 + kg * 8;
        float4 u0 = *(const float4*)(xrow);
        float4 u1 = *(const float4*)(xrow + 4);
        float4 u2 = *(const float4*)(xrow + 32);
        float4 u3 = *(const float4*)(xrow + 36);
        f16x8 A0, A1;
        A0[0] = (_Float16)u0.x; A0[1] = (_Float16)u0.y;
        A0[2] = (_Float16)u0.z; A0[3] = (_Float16)u0.w;
        A0[4] = (_Float16)u1.x; A0[5] = (_Float16)u1.y;
        A0[6] = (_Float16)u1.z; A0[7] = (_Float16)u1.w;
        A1[0] = (_Float16)u2.x; A1[1] = (_Float16)u2.y;
        A1[2] = (_Float16)u2.z; A1[3] = (_Float16)u2.w;
        A1[4] = (_Float16)u3.x; A1[5] = (_Float16)u3.y;
        A1[6] = (_Float16)u3.z; A1[7] = (_Float16)u3.w;

        f32x4 D[17];
        #pragma unroll
        for (int ct = 0; ct < 17; ++ct) {
            f16x8 B0 = *(const f16x8*)&Wl[ct * 16 + r16][kg * 8];
            f16x8 B1 = *(const f16x8*)&Wl[ct * 16 + r16][32 + kg * 8];
            f32x4 d = {0.f, 0.f, 0.f, 0.f};
            d = __builtin_amdgcn_mfma_f32_16x16x32_f16(A0, B0, d, 0, 0, 0);
            d = __builtin_amdgcn_mfma_f32_16x16x32_f16(A1, B1, d, 0, 0, 0);
            D[ct] = d;
        }

        // stores: xh[n][((ct&3)*16+r16)*4 + (ct>>2)] packed 4-at-a-time (8B)
        #pragma unroll
        for (int r = 0; r < 4; ++r) {
            int n = nb + kg * 4 + r;
            #pragma unroll
            for (int j = 0; j < 4; ++j) {
                __half2 lo = __floats2half2_rn(D[j][r], D[j + 4][r]);
                __half2 hi = __floats2half2_rn(D[j + 8][r], D[j + 12][r]);
                uint2 pk;
                pk.x = *(unsigned int*)&lo;
                pk.y = *(unsigned int*)&hi;
                *(uint2*)(xh + (size_t)n * 256 + (j * 16 + r16) * 4) = pk;
            }
            if (r16 < 8) {
                float v = D[16][r];
                int h = r16 >> 1;
                if (r16 & 1) a_dst[n * 4 + h] = v;
                else         a_src[n * 4 + h] = v;
            }
        }
    }
}

// ---------------- histogram (standalone, no LDS) ----------------
__global__ __launch_bounds__(256) void hist_kernel(const int* __restrict__ ei,
                                                   int* __restrict__ counts) {
    int e = blockIdx.x * 256 + threadIdx.x;
    if (e < N_EDGES) atomicAdd(&counts[ei[N_EDGES + e]], 1);
}

// ---------------- scans ----------------
__global__ __launch_bounds__(256) void scan1_kernel(const int* __restrict__ counts,
                                                    int* __restrict__ offsets,
                                                    int* __restrict__ blocksums) {
    __shared__ int sh[256];
    int tid = threadIdx.x;
    int i = blockIdx.x * 256 + tid;
    int v = (i < N_NODES) ? counts[i] : 0;
    sh[tid] = v;
    __syncthreads();
    #pragma unroll
    for (int off = 1; off < 256; off <<= 1) {
        int t = (tid >= off) ? sh[tid - off] : 0;
        __syncthreads();
        sh[tid] += t;
        __syncthreads();
    }
    if (i < N_NODES) offsets[i] = sh[tid] - v;
    if (tid == 255) blocksums[blockIdx.x] = sh[255];
}

__global__ __launch_bounds__(256) void scan2_kernel(int* __restrict__ blocksums,
                                                    int* __restrict__ blockoff) {
    __shared__ int sh[256];
    int tid = threadIdx.x;
    int v = (tid < SCAN_NB) ? blocksums[tid] : 0;
    sh[tid] = v;
    __syncthreads();
    #pragma unroll
    for (int off = 1; off < 256; off <<= 1) {
        int t = (tid >= off) ? sh[tid - off] : 0;
        __syncthreads();
        sh[tid] += t;
        __syncthreads();
    }
    if (tid < SCAN_NB) blockoff[tid] = sh[tid] - v;
}

__global__ __launch_bounds__(256) void scan3_kernel(int* __restrict__ offsets,
                                                    const int* __restrict__ blockoff,
                                                    int* __restrict__ cursor) {
    int i = blockIdx.x * 256 + threadIdx.x;
    if (i < N_NODES) {
        int o = offsets[i] + blockoff[blockIdx.x];
        offsets[i] = o;
        cursor[i] = o;
    }
}

// ---------------- fused: edge_ex (blocks 0..HIST_NB-1) ∥ scatter (rest) ----------------
__global__ __launch_bounds__(256) void fused_ex_scatter(
    const int* __restrict__ ei, const int* __restrict__ etype,
    const float* __restrict__ a_src, const float* __restrict__ a_dst,
    const float* __restrict__ a_edge_r, int* __restrict__ cursor,
    uint2* __restrict__ ex4, int* __restrict__ elist)
{
    int tid = threadIdx.x;
    if (blockIdx.x < HIST_NB) {
        int e = blockIdx.x * 256 + tid;
        if (e >= N_EDGES) return;
        int s = ei[e];
        int d = ei[N_EDGES + e];
        int t = etype[e];
        float4 as = ((const float4*)a_src)[s];
        float4 ad = ((const float4*)a_dst)[d];
        float4 ae = ((const float4*)a_edge_r)[t];

        float b0 = as.x + ad.x + ae.x; b0 = b0 > 0.f ? b0 : NEG_SLOPE * b0;
        float b1 = as.y + ad.y + ae.y; b1 = b1 > 0.f ? b1 : NEG_SLOPE * b1;
        float b2 = as.z + ad.z + ae.z; b2 = b2 > 0.f ? b2 : NEG_SLOPE * b2;
        float b3 = as.w + ad.w + ae.w; b3 = b3 > 0.f ? b3 : NEG_SLOPE * b3;

        __half2 lo = __floats2half2_rn(__expf(b0), __expf(b1));
        __half2 hi = __floats2half2_rn(__expf(b2), __expf(b3));
        uint2 pk;
        pk.x = *(unsigned int*)&lo;
        pk.y = *(unsigned int*)&hi;
        ex4[e] = pk;
    } else {
        int e = (blockIdx.x - HIST_NB) * 256 + tid;
        if (e >= N_EDGES) return;
        int d = ei[N_EDGES + e];
        int pos = atomicAdd(&cursor[d], 1);
        elist[pos] = e;
    }
}

// ---------------- aggregate (2 waves per dst node) ----------------
__global__ __launch_bounds__(256) void aggregate(
    const int* __restrict__ offsets, const int* __restrict__ counts,
    const int* __restrict__ elist, const int* __restrict__ ei,
    const uint2* __restrict__ ex4, const __half* __restrict__ xh,
    const float* __restrict__ bias, float* __restrict__ out)
{
    __shared__ uint2  exsh[4][64];
    __shared__ int    ssh[4][64];
    __shared__ float4 pnum[4][64];
    __shared__ float4 pden[4][64];

    int lane = threadIdx.x & 63;
    int warp = threadIdx.x >> 6;   // 0..3
    int pair = warp >> 1;
    int half = warp & 1;
    int d = blockIdx.x * 2 + pair;

    int beg = offsets[d];
    int deg = counts[d];
    int h1 = (deg + 1) >> 1;
    int mybeg = beg + (half ? h1 : 0);
    int mydeg = half ? (deg - h1) : h1;

    float n0 = 0.f, n1 = 0.f, n2 = 0.f, n3 = 0.f;
    float d0 = 0.f, d1 = 0.f, d2 = 0.f, d3 = 0.f;

    for (int base = 0; base < mydeg; base += 64) {
        int m = mydeg - base; if (m > 64) m = 64;

        uint2 pk = make_uint2(0u, 0u);
        int s = 0;
        if (lane < m) {
            int eid = elist[mybeg + base + lane];
            s = ei[eid];
            pk = ex4[eid];
        }
        {
            __half2 lo = *(__half2*)&pk.x;
            __half2 hi = *(__half2*)&pk.y;
            float2 w01 = __half22float2(lo);
            float2 w23 = __half22float2(hi);
            d0 += w01.x; d1 += w01.y; d2 += w23.x; d3 += w23.y;
        }
        exsh[warp][lane] = pk;   // wave-private rows; wave-synchronous RAW
        ssh[warp][lane]  = s;

        #pragma unroll 4
        for (int j = 0; j < m; ++j) {
            uint2 e2 = exsh[warp][j];
            int sj = ssh[warp][j];
            __half2 lo = *(__half2*)&e2.x;
            __half2 hi = *(__half2*)&e2.y;
            float2 w01 = __half22float2(lo);
            float2 w23 = __half22float2(hi);
            const __half2* __restrict__ xr =
                (const __half2*)(xh + (size_t)sj * 256 + lane * 4);
            __half2 p0 = xr[0], p1 = xr[1];
            float2 f0 = __half22float2(p0), f1 = __half22float2(p1);
            n0 = fmaf(w01.x, f0.x, n0);
            n1 = fmaf(w01.y, f0.y, n1);
            n2 = fmaf(w23.x, f1.x, n2);
            n3 = fmaf(w23.y, f1.y, n3);
        }
    }

    pnum[warp][lane] = make_float4(n0, n1, n2, n3);
    pden[warp][lane] = make_float4(d0, d1, d2, d3);
    __syncthreads();

    if (half == 0) {
        float4 on = pnum[warp + 1][lane];
        float4 od = pden[warp + 1][lane];
        n0 += on.x; n1 += on.y; n2 += on.z; n3 += on.w;
        d0 += od.x; d1 += od.y; d2 += od.z; d3 += od.w;

        #pragma unroll
        for (int msk = 32; msk >= 1; msk >>= 1) {
            d0 += __shfl_xor(d0, msk);
            d1 += __shfl_xor(d1, msk);
            d2 += __shfl_xor(d2, msk);
            d3 += __shfl_xor(d3, msk);
        }

        float r = 0.f;
        if (deg > 0)
            r = 0.25f * (n0 / d0 + n1 / d1 + n2 / d2 + n3 / d3);
        out[(size_t)d * 64 + lane] = r + bias[lane];
    }
}

extern "C" void kernel_launch(void* const* d_in, const int* in_sizes, int n_in,
                              void* d_out, int out_size, void* d_ws, size_t ws_size,
                              hipStream_t stream) {
    const float* x        = (const float*)d_in[0];
    const int*   ei       = (const int*)  d_in[1];
    const int*   etype    = (const int*)  d_in[2];
    const float* rel_emb  = (const float*)d_in[3];
    const float* W        = (const float*)d_in[4];
    const float* W_e      = (const float*)d_in[5];
    const float* att_src  = (const float*)d_in[6];
    const float* att_dst  = (const float*)d_in[7];
    const float* att_edge = (const float*)d_in[8];
    const float* bias     = (const float*)d_in[9];
    float* out = (float*)d_out;

    char* ws = (char*)d_ws;
    __half* xh      = (__half*)ws;                              // 25.6 MB
    char* p = ws + (size_t)N_NODES * 256 * 2;
    int*   counts   = (int*)p;                p += N_NODES * 4;   // zeroed
    float* a_src    = (float*)p;              p += N_NODES * 4 * 4;
    float* a_dst    = (float*)p;              p += N_NODES * 4 * 4;
    float* a_edge_r = (float*)p;              p += NREL * 4 * 4;
    float* vsd      = (float*)p;              p += 8 * 64 * 4;
    int*   offsets  = (int*)p;                p += N_NODES * 4;
    int*   cursor   = (int*)p;                p += N_NODES * 4;
    int*   blocksums= (int*)p;                p += 256 * 4;
    int*   blockoff = (int*)p;                p += 256 * 4;
    int*   elist    = (int*)p;                p += (size_t)N_EDGES * 4;
    uint2* ex4      = (uint2*)p;              p += (size_t)N_EDGES * 8;

    hipMemsetAsync(counts, 0, N_NODES * sizeof(int), stream);
    prep_kernel<<<NREL + 8, 64, 0, stream>>>(rel_emb, W_e, att_edge, a_edge_r,
                                             W, att_src, att_dst, vsd);
    nx_mfma<<<NXB, 256, 0, stream>>>(x, W, vsd, xh, a_src, a_dst);
    hist_kernel<<<HIST_NB, 256, 0, stream>>>(ei, counts);
    scan1_kernel<<<SCAN_NB, 256, 0, stream>>>(counts, offsets, blocksums);
    scan2_kernel<<<1, 256, 0, stream>>>(blocksums, blockoff);
    scan3_kernel<<<SCAN_NB, 256, 0, stream>>>(offsets, blockoff, cursor);
    fused_ex_scatter<<<2 * HIST_NB, 256, 0, stream>>>(ei, etype, a_src, a_dst,
                                                      a_edge_r, cursor, ex4, elist);
    aggregate<<<N_NODES / 2, 256, 0, stream>>>(offsets, counts, elist, ei,
                                               ex4, xh, bias, out);
}

// Round 13
// 188.692 us; speedup vs baseline: 1.9428x; 1.1001x over previous
//
#include <hip/hip_runtime.h>
#include <hip/hip_fp16.h>

#define N_NODES 50000
#define N_EDGES 800000
#define NREL 32
#define NEG_SLOPE 0.2f
#define SCAN_NB ((N_NODES + 255) / 256)   // 196
#define HIST_NB ((N_EDGES + 255) / 256)   // 3125
#define NXB 256                           // nx_mfma grid
#define NTILES (N_NODES / 16)             // 3125 wave tiles (exact)

typedef _Float16 f16x8 __attribute__((ext_vector_type(8)));
typedef float f32x4 __attribute__((ext_vector_type(4)));

// ---------------- prep: relation table (blocks 0..31) + vsd (blocks 32..39) ----------------
__global__ __launch_bounds__(64) void prep_kernel(
    const float* __restrict__ rel_emb, const float* __restrict__ W_e,
    const float* __restrict__ att_edge, float* __restrict__ a_edge_r,
    const float* __restrict__ W, const float* __restrict__ att_src,
    const float* __restrict__ att_dst, float* __restrict__ vsd)
{
    int tid = threadIdx.x;
    if (blockIdx.x < NREL) {
        int r = blockIdx.x;
        int h = tid >> 4;
        int i16 = tid & 15;
        float rr = rel_emb[r * 64 + tid];
        float4 acc = {0.f, 0.f, 0.f, 0.f};
        #pragma unroll
        for (int k = 0; k < 64; ++k) {
            float rv = __shfl(rr, k);
            float4 wv = *(const float4*)(W_e + k * 256 + h * 64 + i16 * 4);
            acc.x += rv * wv.x; acc.y += rv * wv.y;
            acc.z += rv * wv.z; acc.w += rv * wv.w;
        }
        float4 aev = *(const float4*)(att_edge + h * 64 + i16 * 4);
        float ae = acc.x * aev.x + acc.y * aev.y + acc.z * aev.z + acc.w * aev.w;
        #pragma unroll
        for (int m = 8; m >= 1; m >>= 1) ae += __shfl_xor(ae, m);
        if (i16 == 0) a_edge_r[r * 4 + h] = ae;
    } else {
        int col8 = blockIdx.x - NREL;   // 0..7
        int h = col8 >> 1;
        const float* att = (col8 & 1) ? att_dst : att_src;
        int k = tid;
        float s = 0.f;
        #pragma unroll 8
        for (int c = 0; c < 64; ++c)
            s += W[k * 256 + h * 64 + c] * att[h * 64 + c];
        vsd[col8 * 64 + k] = s;
    }
}

// ---------------- node transform via MFMA (proven in round 12) ----------------
__global__ __launch_bounds__(256) void nx_mfma(
    const float* __restrict__ x, const float* __restrict__ W,
    const float* __restrict__ vsd, __half* __restrict__ xh,
    float* __restrict__ a_src, float* __restrict__ a_dst)
{
    __shared__ __align__(16) _Float16 Wl[272][72];
    int tid = threadIdx.x;

    for (int idx = tid; idx < 64 * 256; idx += 256) {
        int k = idx >> 8, col = idx & 255;
        Wl[col][k] = (_Float16)W[idx];
    }
    for (int idx = tid; idx < 64 * 16; idx += 256) {
        int k = idx >> 4, col8 = idx & 15;
        Wl[256 + col8][k] = (_Float16)((col8 < 8) ? vsd[col8 * 64 + k] : 0.f);
    }
    __syncthreads();

    int lane = tid & 63;
    int wv = tid >> 6;
    int r16 = lane & 15;
    int kg = lane >> 4;

    for (int tile = blockIdx.x * 4 + wv; tile < NTILES; tile += NXB * 4) {
        int nb = tile * 16;
        const float* __restrict__ xrow = x + (size_t)(nb + r16) * 64 + kg * 8;
        float4 u0 = *(const float4*)(xrow);
        float4 u1 = *(const float4*)(xrow + 4);
        float4 u2 = *(const float4*)(xrow + 32);
        float4 u3 = *(const float4*)(xrow + 36);
        f16x8 A0, A1;
        A0[0] = (_Float16)u0.x; A0[1] = (_Float16)u0.y;
        A0[2] = (_Float16)u0.z; A0[3] = (_Float16)u0.w;
        A0[4] = (_Float16)u1.x; A0[5] = (_Float16)u1.y;
        A0[6] = (_Float16)u1.z; A0[7] = (_Float16)u1.w;
        A1[0] = (_Float16)u2.x; A1[1] = (_Float16)u2.y;
        A1[2] = (_Float16)u2.z; A1[3] = (_Float16)u2.w;
        A1[4] = (_Float16)u3.x; A1[5] = (_Float16)u3.y;
        A1[6] = (_Float16)u3.z; A1[7] = (_Float16)u3.w;

        f32x4 D[17];
        #pragma unroll
        for (int ct = 0; ct < 17; ++ct) {
            f16x8 B0 = *(const f16x8*)&Wl[ct * 16 + r16][kg * 8];
            f16x8 B1 = *(const f16x8*)&Wl[ct * 16 + r16][32 + kg * 8];
            f32x4 d = {0.f, 0.f, 0.f, 0.f};
            d = __builtin_amdgcn_mfma_f32_16x16x32_f16(A0, B0, d, 0, 0, 0);
            d = __builtin_amdgcn_mfma_f32_16x16x32_f16(A1, B1, d, 0, 0, 0);
            D[ct] = d;
        }

        #pragma unroll
        for (int r = 0; r < 4; ++r) {
            int n = nb + kg * 4 + r;
            #pragma unroll
            for (int j = 0; j < 4; ++j) {
                __half2 lo = __floats2half2_rn(D[j][r], D[j + 4][r]);
                __half2 hi = __floats2half2_rn(D[j + 8][r], D[j + 12][r]);
                uint2 pk;
                pk.x = *(unsigned int*)&lo;
                pk.y = *(unsigned int*)&hi;
                *(uint2*)(xh + (size_t)n * 256 + (j * 16 + r16) * 4) = pk;
            }
            if (r16 < 8) {
                float v = D[16][r];
                int h = r16 >> 1;
                if (r16 & 1) a_dst[n * 4 + h] = v;
                else         a_src[n * 4 + h] = v;
            }
        }
    }
}

// ---------------- histogram ----------------
__global__ __launch_bounds__(256) void hist_kernel(const int* __restrict__ ei,
                                                   int* __restrict__ counts) {
    int e = blockIdx.x * 256 + threadIdx.x;
    if (e < N_EDGES) atomicAdd(&counts[ei[N_EDGES + e]], 1);
}

// ---------------- scans ----------------
__global__ __launch_bounds__(256) void scan1_kernel(const int* __restrict__ counts,
                                                    int* __restrict__ offsets,
                                                    int* __restrict__ blocksums) {
    __shared__ int sh[256];
    int tid = threadIdx.x;
    int i = blockIdx.x * 256 + tid;
    int v = (i < N_NODES) ? counts[i] : 0;
    sh[tid] = v;
    __syncthreads();
    #pragma unroll
    for (int off = 1; off < 256; off <<= 1) {
        int t = (tid >= off) ? sh[tid - off] : 0;
        __syncthreads();
        sh[tid] += t;
        __syncthreads();
    }
    if (i < N_NODES) offsets[i] = sh[tid] - v;
    if (tid == 255) blocksums[blockIdx.x] = sh[255];
}

__global__ __launch_bounds__(256) void scan2_kernel(int* __restrict__ blocksums,
                                                    int* __restrict__ blockoff) {
    __shared__ int sh[256];
    int tid = threadIdx.x;
    int v = (tid < SCAN_NB) ? blocksums[tid] : 0;
    sh[tid] = v;
    __syncthreads();
    #pragma unroll
    for (int off = 1; off < 256; off <<= 1) {
        int t = (tid >= off) ? sh[tid - off] : 0;
        __syncthreads();
        sh[tid] += t;
        __syncthreads();
    }
    if (tid < SCAN_NB) blockoff[tid] = sh[tid] - v;
}

__global__ __launch_bounds__(256) void scan3_kernel(int* __restrict__ offsets,
                                                    const int* __restrict__ blockoff,
                                                    int* __restrict__ cursor) {
    int i = blockIdx.x * 256 + threadIdx.x;
    if (i < N_NODES) {
        int o = offsets[i] + blockoff[blockIdx.x];
        offsets[i] = o;
        cursor[i] = o;
    }
}

// ---------------- scatter: elist[pos] = (s<<5)|t  (4B, single dirty line) ----------------
__global__ __launch_bounds__(256) void scatter_kernel(const int* __restrict__ ei,
                                                      const int* __restrict__ etype,
                                                      int* __restrict__ cursor,
                                                      int* __restrict__ elist) {
    int e = blockIdx.x * 256 + threadIdx.x;
    if (e >= N_EDGES) return;
    int s = ei[e];
    int d = ei[N_EDGES + e];
    int t = etype[e];
    int pos = atomicAdd(&cursor[d], 1);
    elist[pos] = (s << 5) | t;
}

// ---------------- aggregate (round-9 form: 2 waves/node, inline exp) ----------------
__global__ __launch_bounds__(256) void aggregate(
    const int* __restrict__ offsets, const int* __restrict__ counts,
    const int* __restrict__ elist, const float* __restrict__ a_src,
    const float* __restrict__ a_dst, const float* __restrict__ a_edge_r,
    const __half* __restrict__ xh, const float* __restrict__ bias,
    float* __restrict__ out)
{
    __shared__ float4 exsh[4][64];
    __shared__ int    ssh[4][64];
    __shared__ float4 pnum[4][64];
    __shared__ float4 pden[4][64];

    int lane = threadIdx.x & 63;
    int warp = threadIdx.x >> 6;   // 0..3
    int pair = warp >> 1;
    int half = warp & 1;
    int d = blockIdx.x * 2 + pair;

    int beg = offsets[d];
    int deg = counts[d];
    int h1 = (deg + 1) >> 1;
    int mybeg = beg + (half ? h1 : 0);
    int mydeg = half ? (deg - h1) : h1;

    float4 advec = ((const float4*)a_dst)[d];

    float n0 = 0.f, n1 = 0.f, n2 = 0.f, n3 = 0.f;
    float d0 = 0.f, d1 = 0.f, d2 = 0.f, d3 = 0.f;

    for (int base = 0; base < mydeg; base += 64) {
        int m = mydeg - base; if (m > 64) m = 64;

        float4 ev = make_float4(0.f, 0.f, 0.f, 0.f);
        int s = 0;
        if (lane < m) {
            int pk = elist[mybeg + base + lane];
            s = pk >> 5;
            int t = pk & 31;
            float4 as = ((const float4*)a_src)[s];
            float4 ae = ((const float4*)a_edge_r)[t];
            float b0 = as.x + advec.x + ae.x; b0 = b0 > 0.f ? b0 : NEG_SLOPE * b0;
            float b1 = as.y + advec.y + ae.y; b1 = b1 > 0.f ? b1 : NEG_SLOPE * b1;
            float b2 = as.z + advec.z + ae.z; b2 = b2 > 0.f ? b2 : NEG_SLOPE * b2;
            float b3 = as.w + advec.w + ae.w; b3 = b3 > 0.f ? b3 : NEG_SLOPE * b3;
            ev.x = __expf(b0); ev.y = __expf(b1);
            ev.z = __expf(b2); ev.w = __expf(b3);
        }
        d0 += ev.x; d1 += ev.y; d2 += ev.z; d3 += ev.w;
        exsh[warp][lane] = ev;   // wave-private rows; wave-synchronous RAW
        ssh[warp][lane]  = s;

        #pragma unroll 4
        for (int j = 0; j < m; ++j) {
            float4 e = exsh[warp][j];   // broadcast read (no conflict)
            int sj = ssh[warp][j];
            const __half2* __restrict__ xr =
                (const __half2*)(xh + (size_t)sj * 256 + lane * 4);
            __half2 p0 = xr[0], p1 = xr[1];
            float2 f0 = __half22float2(p0), f1 = __half22float2(p1);
            n0 = fmaf(e.x, f0.x, n0);
            n1 = fmaf(e.y, f0.y, n1);
            n2 = fmaf(e.z, f1.x, n2);
            n3 = fmaf(e.w, f1.y, n3);
        }
    }

    pnum[warp][lane] = make_float4(n0, n1, n2, n3);
    pden[warp][lane] = make_float4(d0, d1, d2, d3);
    __syncthreads();

    if (half == 0) {
        float4 on = pnum[warp + 1][lane];
        float4 od = pden[warp + 1][lane];
        n0 += on.x; n1 += on.y; n2 += on.z; n3 += on.w;
        d0 += od.x; d1 += od.y; d2 += od.z; d3 += od.w;

        #pragma unroll
        for (int msk = 32; msk >= 1; msk >>= 1) {
            d0 += __shfl_xor(d0, msk);
            d1 += __shfl_xor(d1, msk);
            d2 += __shfl_xor(d2, msk);
            d3 += __shfl_xor(d3, msk);
        }

        float r = 0.f;
        if (deg > 0)
            r = 0.25f * (n0 / d0 + n1 / d1 + n2 / d2 + n3 / d3);
        out[(size_t)d * 64 + lane] = r + bias[lane];
    }
}

extern "C" void kernel_launch(void* const* d_in, const int* in_sizes, int n_in,
                              void* d_out, int out_size, void* d_ws, size_t ws_size,
                              hipStream_t stream) {
    const float* x        = (const float*)d_in[0];
    const int*   ei       = (const int*)  d_in[1];
    const int*   etype    = (const int*)  d_in[2];
    const float* rel_emb  = (const float*)d_in[3];
    const float* W        = (const float*)d_in[4];
    const float* W_e      = (const float*)d_in[5];
    const float* att_src  = (const float*)d_in[6];
    const float* att_dst  = (const float*)d_in[7];
    const float* att_edge = (const float*)d_in[8];
    const float* bias     = (const float*)d_in[9];
    float* out = (float*)d_out;

    char* ws = (char*)d_ws;
    __half* xh      = (__half*)ws;                              // 25.6 MB
    char* p = ws + (size_t)N_NODES * 256 * 2;
    int*   counts   = (int*)p;                p += N_NODES * 4;   // zeroed
    float* a_src    = (float*)p;              p += N_NODES * 4 * 4;
    float* a_dst    = (float*)p;              p += N_NODES * 4 * 4;
    float* a_edge_r = (float*)p;              p += NREL * 4 * 4;
    float* vsd      = (float*)p;              p += 8 * 64 * 4;
    int*   offsets  = (int*)p;                p += N_NODES * 4;
    int*   cursor   = (int*)p;                p += N_NODES * 4;
    int*   blocksums= (int*)p;                p += 256 * 4;
    int*   blockoff = (int*)p;                p += 256 * 4;
    int*   elist    = (int*)p;                p += (size_t)N_EDGES * 4;

    hipMemsetAsync(counts, 0, N_NODES * sizeof(int), stream);
    prep_kernel<<<NREL + 8, 64, 0, stream>>>(rel_emb, W_e, att_edge, a_edge_r,
                                             W, att_src, att_dst, vsd);
    nx_mfma<<<NXB, 256, 0, stream>>>(x, W, vsd, xh, a_src, a_dst);
    hist_kernel<<<HIST_NB, 256, 0, stream>>>(ei, counts);
    scan1_kernel<<<SCAN_NB, 256, 0, stream>>>(counts, offsets, blocksums);
    scan2_kernel<<<1, 256, 0, stream>>>(blocksums, blockoff);
    scan3_kernel<<<SCAN_NB, 256, 0, stream>>>(offsets, blockoff, cursor);
    scatter_kernel<<<HIST_NB, 256, 0, stream>>>(ei, etype, cursor, elist);
    aggregate<<<N_NODES / 2, 256, 0, stream>>>(offsets, counts, elist, a_src,
                                               a_dst, a_edge_r, xh, bias, out);
}

// Round 14
// 153.210 us; speedup vs baseline: 2.3927x; 1.2316x over previous
//
#include <hip/hip_runtime.h>
#include <hip/hip_fp16.h>

#define N_NODES 50000
#define N_EDGES 800000
#define NREL 32
#define NEG_SLOPE 0.2f
#define SCAN_NB ((N_NODES + 255) / 256)   // 196
#define HIST_NB ((N_EDGES + 255) / 256)   // 3125
#define NXB 256                           // nx_mfma grid
#define NTILES (N_NODES / 16)             // 3125 wave tiles (exact)

typedef _Float16 f16x8 __attribute__((ext_vector_type(8)));
typedef float f32x4 __attribute__((ext_vector_type(4)));

// ---------------- prep: relation table (blocks 0..31) + vsd (blocks 32..39) ----------------
__global__ __launch_bounds__(64) void prep_kernel(
    const float* __restrict__ rel_emb, const float* __restrict__ W_e,
    const float* __restrict__ att_edge, float* __restrict__ a_edge_r,
    const float* __restrict__ W, const float* __restrict__ att_src,
    const float* __restrict__ att_dst, float* __restrict__ vsd)
{
    int tid = threadIdx.x;
    if (blockIdx.x < NREL) {
        int r = blockIdx.x;
        int h = tid >> 4;
        int i16 = tid & 15;
        float rr = rel_emb[r * 64 + tid];
        float4 acc = {0.f, 0.f, 0.f, 0.f};
        #pragma unroll
        for (int k = 0; k < 64; ++k) {
            float rv = __shfl(rr, k);
            float4 wv = *(const float4*)(W_e + k * 256 + h * 64 + i16 * 4);
            acc.x += rv * wv.x; acc.y += rv * wv.y;
            acc.z += rv * wv.z; acc.w += rv * wv.w;
        }
        float4 aev = *(const float4*)(att_edge + h * 64 + i16 * 4);
        float ae = acc.x * aev.x + acc.y * aev.y + acc.z * aev.z + acc.w * aev.w;
        #pragma unroll
        for (int m = 8; m >= 1; m >>= 1) ae += __shfl_xor(ae, m);
        if (i16 == 0) a_edge_r[r * 4 + h] = ae;
    } else {
        int col8 = blockIdx.x - NREL;   // 0..7
        int h = col8 >> 1;
        const float* att = (col8 & 1) ? att_dst : att_src;
        int k = tid;
        float s = 0.f;
        #pragma unroll 8
        for (int c = 0; c < 64; ++c)
            s += W[k * 256 + h * 64 + c] * att[h * 64 + c];
        vsd[col8 * 64 + k] = s;
    }
}

// ---------------- node transform via MFMA (proven) ----------------
__global__ __launch_bounds__(256) void nx_mfma(
    const float* __restrict__ x, const float* __restrict__ W,
    const float* __restrict__ vsd, __half* __restrict__ xh,
    float* __restrict__ a_src, float* __restrict__ a_dst)
{
    __shared__ __align__(16) _Float16 Wl[272][72];
    int tid = threadIdx.x;

    for (int idx = tid; idx < 64 * 256; idx += 256) {
        int k = idx >> 8, col = idx & 255;
        Wl[col][k] = (_Float16)W[idx];
    }
    for (int idx = tid; idx < 64 * 16; idx += 256) {
        int k = idx >> 4, col8 = idx & 15;
        Wl[256 + col8][k] = (_Float16)((col8 < 8) ? vsd[col8 * 64 + k] : 0.f);
    }
    __syncthreads();

    int lane = tid & 63;
    int wv = tid >> 6;
    int r16 = lane & 15;
    int kg = lane >> 4;

    for (int tile = blockIdx.x * 4 + wv; tile < NTILES; tile += NXB * 4) {
        int nb = tile * 16;
        const float* __restrict__ xrow = x + (size_t)(nb + r16) * 64 + kg * 8;
        float4 u0 = *(const float4*)(xrow);
        float4 u1 = *(const float4*)(xrow + 4);
        float4 u2 = *(const float4*)(xrow + 32);
        float4 u3 = *(const float4*)(xrow + 36);
        f16x8 A0, A1;
        A0[0] = (_Float16)u0.x; A0[1] = (_Float16)u0.y;
        A0[2] = (_Float16)u0.z; A0[3] = (_Float16)u0.w;
        A0[4] = (_Float16)u1.x; A0[5] = (_Float16)u1.y;
        A0[6] = (_Float16)u1.z; A0[7] = (_Float16)u1.w;
        A1[0] = (_Float16)u2.x; A1[1] = (_Float16)u2.y;
        A1[2] = (_Float16)u2.z; A1[3] = (_Float16)u2.w;
        A1[4] = (_Float16)u3.x; A1[5] = (_Float16)u3.y;
        A1[6] = (_Float16)u3.z; A1[7] = (_Float16)u3.w;

        f32x4 D[17];
        #pragma unroll
        for (int ct = 0; ct < 17; ++ct) {
            f16x8 B0 = *(const f16x8*)&Wl[ct * 16 + r16][kg * 8];
            f16x8 B1 = *(const f16x8*)&Wl[ct * 16 + r16][32 + kg * 8];
            f32x4 d = {0.f, 0.f, 0.f, 0.f};
            d = __builtin_amdgcn_mfma_f32_16x16x32_f16(A0, B0, d, 0, 0, 0);
            d = __builtin_amdgcn_mfma_f32_16x16x32_f16(A1, B1, d, 0, 0, 0);
            D[ct] = d;
        }

        #pragma unroll
        for (int r = 0; r < 4; ++r) {
            int n = nb + kg * 4 + r;
            #pragma unroll
            for (int j = 0; j < 4; ++j) {
                __half2 lo = __floats2half2_rn(D[j][r], D[j + 4][r]);
                __half2 hi = __floats2half2_rn(D[j + 8][r], D[j + 12][r]);
                uint2 pk;
                pk.x = *(unsigned int*)&lo;
                pk.y = *(unsigned int*)&hi;
                *(uint2*)(xh + (size_t)n * 256 + (j * 16 + r16) * 4) = pk;
            }
            if (r16 < 8) {
                float v = D[16][r];
                int h = r16 >> 1;
                if (r16 & 1) a_dst[n * 4 + h] = v;
                else         a_src[n * 4 + h] = v;
            }
        }
    }
}

// ---------------- histogram + rank (atomic return value is free) ----------------
__global__ __launch_bounds__(256) void hist_kernel(const int* __restrict__ ei,
                                                   int* __restrict__ counts,
                                                   int* __restrict__ rank) {
    int e = blockIdx.x * 256 + threadIdx.x;
    if (e < N_EDGES) rank[e] = atomicAdd(&counts[ei[N_EDGES + e]], 1);
}

// ---------------- scan1: block-level exclusive scan ----------------
__global__ __launch_bounds__(256) void scan1_kernel(const int* __restrict__ counts,
                                                    int* __restrict__ offsets,
                                                    int* __restrict__ blocksums) {
    __shared__ int sh[256];
    int tid = threadIdx.x;
    int i = blockIdx.x * 256 + tid;
    int v = (i < N_NODES) ? counts[i] : 0;
    sh[tid] = v;
    __syncthreads();
    #pragma unroll
    for (int off = 1; off < 256; off <<= 1) {
        int t = (tid >= off) ? sh[tid - off] : 0;
        __syncthreads();
        sh[tid] += t;
        __syncthreads();
    }
    if (i < N_NODES) offsets[i] = sh[tid] - v;
    if (tid == 255) blocksums[blockIdx.x] = sh[255];
}

// ---------------- scan23: each block derives its own offset via masked reduce ----------------
__global__ __launch_bounds__(256) void scan23_kernel(int* __restrict__ offsets,
                                                     const int* __restrict__ blocksums) {
    __shared__ int wsum[4];
    int tid = threadIdx.x;
    int lane = tid & 63;
    int warp = tid >> 6;

    int v = (tid < SCAN_NB && tid < (int)blockIdx.x) ? blocksums[tid] : 0;
    #pragma unroll
    for (int m = 32; m >= 1; m >>= 1) v += __shfl_xor(v, m);
    if (lane == 0) wsum[warp] = v;
    __syncthreads();
    int boff = wsum[0] + wsum[1] + wsum[2] + wsum[3];

    int i = blockIdx.x * 256 + tid;
    if (i < N_NODES) offsets[i] += boff;
}

// ---------------- scatter: pos = offsets[d] + rank[e]  (no atomic) ----------------
__global__ __launch_bounds__(256) void scatter_kernel(const int* __restrict__ ei,
                                                      const int* __restrict__ etype,
                                                      const int* __restrict__ offsets,
                                                      const int* __restrict__ rank,
                                                      int* __restrict__ elist) {
    int e = blockIdx.x * 256 + threadIdx.x;
    if (e >= N_EDGES) return;
    int s = ei[e];
    int d = ei[N_EDGES + e];
    int t = etype[e];
    int pos = offsets[d] + rank[e];
    elist[pos] = (s << 5) | t;
}

// ---------------- aggregate (2 waves per dst node, inline exp) ----------------
__global__ __launch_bounds__(256) void aggregate(
    const int* __restrict__ offsets, const int* __restrict__ counts,
    const int* __restrict__ elist, const float* __restrict__ a_src,
    const float* __restrict__ a_dst, const float* __restrict__ a_edge_r,
    const __half* __restrict__ xh, const float* __restrict__ bias,
    float* __restrict__ out)
{
    __shared__ float4 exsh[4][64];
    __shared__ int    ssh[4][64];
    __shared__ float4 pnum[4][64];
    __shared__ float4 pden[4][64];

    int lane = threadIdx.x & 63;
    int warp = threadIdx.x >> 6;   // 0..3
    int pair = warp >> 1;
    int half = warp & 1;
    int d = blockIdx.x * 2 + pair;

    int beg = offsets[d];
    int deg = counts[d];
    int h1 = (deg + 1) >> 1;
    int mybeg = beg + (half ? h1 : 0);
    int mydeg = half ? (deg - h1) : h1;

    float4 advec = ((const float4*)a_dst)[d];

    float n0 = 0.f, n1 = 0.f, n2 = 0.f, n3 = 0.f;
    float d0 = 0.f, d1 = 0.f, d2 = 0.f, d3 = 0.f;

    for (int base = 0; base < mydeg; base += 64) {
        int m = mydeg - base; if (m > 64) m = 64;

        float4 ev = make_float4(0.f, 0.f, 0.f, 0.f);
        int s = 0;
        if (lane < m) {
            int pk = elist[mybeg + base + lane];
            s = pk >> 5;
            int t = pk & 31;
            float4 as = ((const float4*)a_src)[s];
            float4 ae = ((const float4*)a_edge_r)[t];
            float b0 = as.x + advec.x + ae.x; b0 = b0 > 0.f ? b0 : NEG_SLOPE * b0;
            float b1 = as.y + advec.y + ae.y; b1 = b1 > 0.f ? b1 : NEG_SLOPE * b1;
            float b2 = as.z + advec.z + ae.z; b2 = b2 > 0.f ? b2 : NEG_SLOPE * b2;
            float b3 = as.w + advec.w + ae.w; b3 = b3 > 0.f ? b3 : NEG_SLOPE * b3;
            ev.x = __expf(b0); ev.y = __expf(b1);
            ev.z = __expf(b2); ev.w = __expf(b3);
        }
        d0 += ev.x; d1 += ev.y; d2 += ev.z; d3 += ev.w;
        exsh[warp][lane] = ev;   // wave-private rows; wave-synchronous RAW
        ssh[warp][lane]  = s;

        #pragma unroll 4
        for (int j = 0; j < m; ++j) {
            float4 e = exsh[warp][j];   // broadcast read (no conflict)
            int sj = ssh[warp][j];
            const __half2* __restrict__ xr =
                (const __half2*)(xh + (size_t)sj * 256 + lane * 4);
            __half2 p0 = xr[0], p1 = xr[1];
            float2 f0 = __half22float2(p0), f1 = __half22float2(p1);
            n0 = fmaf(e.x, f0.x, n0);
            n1 = fmaf(e.y, f0.y, n1);
            n2 = fmaf(e.z, f1.x, n2);
            n3 = fmaf(e.w, f1.y, n3);
        }
    }

    pnum[warp][lane] = make_float4(n0, n1, n2, n3);
    pden[warp][lane] = make_float4(d0, d1, d2, d3);
    __syncthreads();

    if (half == 0) {
        float4 on = pnum[warp + 1][lane];
        float4 od = pden[warp + 1][lane];
        n0 += on.x; n1 += on.y; n2 += on.z; n3 += on.w;
        d0 += od.x; d1 += od.y; d2 += od.z; d3 += od.w;

        #pragma unroll
        for (int msk = 32; msk >= 1; msk >>= 1) {
            d0 += __shfl_xor(d0, msk);
            d1 += __shfl_xor(d1, msk);
            d2 += __shfl_xor(d2, msk);
            d3 += __shfl_xor(d3, msk);
        }

        float r = 0.f;
        if (deg > 0)
            r = 0.25f * (n0 / d0 + n1 / d1 + n2 / d2 + n3 / d3);
        out[(size_t)d * 64 + lane] = r + bias[lane];
    }
}

extern "C" void kernel_launch(void* const* d_in, const int* in_sizes, int n_in,
                              void* d_out, int out_size, void* d_ws, size_t ws_size,
                              hipStream_t stream) {
    const float* x        = (const float*)d_in[0];
    const int*   ei       = (const int*)  d_in[1];
    const int*   etype    = (const int*)  d_in[2];
    const float* rel_emb  = (const float*)d_in[3];
    const float* W        = (const float*)d_in[4];
    const float* W_e      = (const float*)d_in[5];
    const float* att_src  = (const float*)d_in[6];
    const float* att_dst  = (const float*)d_in[7];
    const float* att_edge = (const float*)d_in[8];
    const float* bias     = (const float*)d_in[9];
    float* out = (float*)d_out;

    char* ws = (char*)d_ws;
    __half* xh      = (__half*)ws;                              // 25.6 MB
    char* p = ws + (size_t)N_NODES * 256 * 2;
    int*   counts   = (int*)p;                p += N_NODES * 4;   // zeroed
    float* a_src    = (float*)p;              p += N_NODES * 4 * 4;
    float* a_dst    = (float*)p;              p += N_NODES * 4 * 4;
    float* a_edge_r = (float*)p;              p += NREL * 4 * 4;
    float* vsd      = (float*)p;              p += 8 * 64 * 4;
    int*   offsets  = (int*)p;                p += N_NODES * 4;
    int*   blocksums= (int*)p;                p += 256 * 4;
    int*   rank     = (int*)p;                p += (size_t)N_EDGES * 4;
    int*   elist    = (int*)p;                p += (size_t)N_EDGES * 4;

    hipMemsetAsync(counts, 0, N_NODES * sizeof(int), stream);
    prep_kernel<<<NREL + 8, 64, 0, stream>>>(rel_emb, W_e, att_edge, a_edge_r,
                                             W, att_src, att_dst, vsd);
    nx_mfma<<<NXB, 256, 0, stream>>>(x, W, vsd, xh, a_src, a_dst);
    hist_kernel<<<HIST_NB, 256, 0, stream>>>(ei, counts, rank);
    scan1_kernel<<<SCAN_NB, 256, 0, stream>>>(counts, offsets, blocksums);
    scan23_kernel<<<SCAN_NB, 256, 0, stream>>>(offsets, blocksums);
    scatter_kernel<<<HIST_NB, 256, 0, stream>>>(ei, etype, offsets, rank, elist);
    aggregate<<<N_NODES / 2, 256, 0, stream>>>(offsets, counts, elist, a_src,
                                               a_dst, a_edge_r, xh, bias, out);
}

// Round 15
// 147.466 us; speedup vs baseline: 2.4859x; 1.0390x over previous
//
#include <hip/hip_runtime.h>
#include <hip/hip_fp16.h>

#define N_NODES 50000
#define N_EDGES 800000
#define NREL 32
#define NEG_SLOPE 0.2f
#define SCAN_NB ((N_NODES + 255) / 256)   // 196
#define HIST_NB ((N_EDGES + 255) / 256)   // 3125
#define NXB 256                           // nx blocks in MEGA
#define NTILES (N_NODES / 16)             // 3125 wave tiles (exact)

typedef _Float16 f16x8 __attribute__((ext_vector_type(8)));
typedef float f32x4 __attribute__((ext_vector_type(4)));

// ---------------- MEGA: nx_mfma (blocks 0..255) ∥ hist (256..3380) ∥ rel (3381..3412) ----------------
__global__ __launch_bounds__(256) void mega_kernel(
    const float* __restrict__ x, const float* __restrict__ W,
    const float* __restrict__ att_src, const float* __restrict__ att_dst,
    __half* __restrict__ xh, float* __restrict__ a_src, float* __restrict__ a_dst,
    const int* __restrict__ ei, int* __restrict__ counts, int* __restrict__ rank,
    const float* __restrict__ rel_emb, const float* __restrict__ W_e,
    const float* __restrict__ att_edge, float* __restrict__ a_edge_r)
{
    __shared__ __align__(16) _Float16 Wl[272][72];
    int tid = threadIdx.x;
    int bid = blockIdx.x;

    if (bid >= NXB) {
        if (bid < NXB + HIST_NB) {
            // ---- histogram + rank ----
            int e = (bid - NXB) * 256 + tid;
            if (e < N_EDGES) rank[e] = atomicAdd(&counts[ei[N_EDGES + e]], 1);
        } else if (tid < 64) {
            // ---- relation table row r ----
            int r = bid - (NXB + HIST_NB);
            int h = tid >> 4;
            int i16 = tid & 15;
            float rr = rel_emb[r * 64 + tid];
            float4 acc = {0.f, 0.f, 0.f, 0.f};
            #pragma unroll
            for (int k = 0; k < 64; ++k) {
                float rv = __shfl(rr, k);
                float4 wv = *(const float4*)(W_e + k * 256 + h * 64 + i16 * 4);
                acc.x += rv * wv.x; acc.y += rv * wv.y;
                acc.z += rv * wv.z; acc.w += rv * wv.w;
            }
            float4 aev = *(const float4*)(att_edge + h * 64 + i16 * 4);
            float ae = acc.x * aev.x + acc.y * aev.y + acc.z * aev.z + acc.w * aev.w;
            #pragma unroll
            for (int m = 8; m >= 1; m >>= 1) ae += __shfl_xor(ae, m);
            if (i16 == 0) a_edge_r[r * 4 + h] = ae;
        }
        return;
    }

    // ---- node transform via MFMA ----
    for (int idx = tid; idx < 64 * 256; idx += 256) {
        int k = idx >> 8, col = idx & 255;
        Wl[col][k] = (_Float16)W[idx];
    }
    // vsd computed inline (fp32 accumulate): cols 256..263; zero 264..271
    for (int idx = tid; idx < 512; idx += 256) {
        int k = idx & 63;
        int col8 = idx >> 6;
        int h = col8 >> 1;
        const float* att = (col8 & 1) ? att_dst : att_src;
        float s = 0.f;
        #pragma unroll 8
        for (int c = 0; c < 64; ++c)
            s += W[k * 256 + h * 64 + c] * att[h * 64 + c];
        Wl[256 + col8][k] = (_Float16)s;
        Wl[264 + col8][k] = (_Float16)0.f;
    }
    __syncthreads();

    int lane = tid & 63;
    int wv = tid >> 6;
    int r16 = lane & 15;
    int kg = lane >> 4;

    for (int tile = bid * 4 + wv; tile < NTILES; tile += NXB * 4) {
        int nb = tile * 16;
        const float* __restrict__ xrow = x + (size_t)(nb + r16) * 64 + kg * 8;
        float4 u0 = *(const float4*)(xrow);
        float4 u1 = *(const float4*)(xrow + 4);
        float4 u2 = *(const float4*)(xrow + 32);
        float4 u3 = *(const float4*)(xrow + 36);
        f16x8 A0, A1;
        A0[0] = (_Float16)u0.x; A0[1] = (_Float16)u0.y;
        A0[2] = (_Float16)u0.z; A0[3] = (_Float16)u0.w;
        A0[4] = (_Float16)u1.x; A0[5] = (_Float16)u1.y;
        A0[6] = (_Float16)u1.z; A0[7] = (_Float16)u1.w;
        A1[0] = (_Float16)u2.x; A1[1] = (_Float16)u2.y;
        A1[2] = (_Float16)u2.z; A1[3] = (_Float16)u2.w;
        A1[4] = (_Float16)u3.x; A1[5] = (_Float16)u3.y;
        A1[6] = (_Float16)u3.z; A1[7] = (_Float16)u3.w;

        f32x4 D[17];
        #pragma unroll
        for (int ct = 0; ct < 17; ++ct) {
            f16x8 B0 = *(const f16x8*)&Wl[ct * 16 + r16][kg * 8];
            f16x8 B1 = *(const f16x8*)&Wl[ct * 16 + r16][32 + kg * 8];
            f32x4 d = {0.f, 0.f, 0.f, 0.f};
            d = __builtin_amdgcn_mfma_f32_16x16x32_f16(A0, B0, d, 0, 0, 0);
            d = __builtin_amdgcn_mfma_f32_16x16x32_f16(A1, B1, d, 0, 0, 0);
            D[ct] = d;
        }

        #pragma unroll
        for (int r = 0; r < 4; ++r) {
            int n = nb + kg * 4 + r;
            #pragma unroll
            for (int j = 0; j < 4; ++j) {
                __half2 lo = __floats2half2_rn(D[j][r], D[j + 4][r]);
                __half2 hi = __floats2half2_rn(D[j + 8][r], D[j + 12][r]);
                uint2 pk;
                pk.x = *(unsigned int*)&lo;
                pk.y = *(unsigned int*)&hi;
                *(uint2*)(xh + (size_t)n * 256 + (j * 16 + r16) * 4) = pk;
            }
            if (r16 < 8) {
                float v = D[16][r];
                int h = r16 >> 1;
                if (r16 & 1) a_dst[n * 4 + h] = v;
                else         a_src[n * 4 + h] = v;
            }
        }
    }
}

// ---------------- scan1: block-level exclusive scan ----------------
__global__ __launch_bounds__(256) void scan1_kernel(const int* __restrict__ counts,
                                                    int* __restrict__ offsets,
                                                    int* __restrict__ blocksums) {
    __shared__ int sh[256];
    int tid = threadIdx.x;
    int i = blockIdx.x * 256 + tid;
    int v = (i < N_NODES) ? counts[i] : 0;
    sh[tid] = v;
    __syncthreads();
    #pragma unroll
    for (int off = 1; off < 256; off <<= 1) {
        int t = (tid >= off) ? sh[tid - off] : 0;
        __syncthreads();
        sh[tid] += t;
        __syncthreads();
    }
    if (i < N_NODES) offsets[i] = sh[tid] - v;
    if (tid == 255) blocksums[blockIdx.x] = sh[255];
}

// ---------------- scan23: each block derives its own offset via masked reduce ----------------
__global__ __launch_bounds__(256) void scan23_kernel(int* __restrict__ offsets,
                                                     const int* __restrict__ blocksums) {
    __shared__ int wsum[4];
    int tid = threadIdx.x;
    int lane = tid & 63;
    int warp = tid >> 6;

    int v = (tid < SCAN_NB && tid < (int)blockIdx.x) ? blocksums[tid] : 0;
    #pragma unroll
    for (int m = 32; m >= 1; m >>= 1) v += __shfl_xor(v, m);
    if (lane == 0) wsum[warp] = v;
    __syncthreads();
    int boff = wsum[0] + wsum[1] + wsum[2] + wsum[3];

    int i = blockIdx.x * 256 + tid;
    if (i < N_NODES) offsets[i] += boff;
}

// ---------------- scatter: pos = offsets[d] + rank[e]  (no atomic) ----------------
__global__ __launch_bounds__(256) void scatter_kernel(const int* __restrict__ ei,
                                                      const int* __restrict__ etype,
                                                      const int* __restrict__ offsets,
                                                      const int* __restrict__ rank,
                                                      int* __restrict__ elist) {
    int e = blockIdx.x * 256 + threadIdx.x;
    if (e >= N_EDGES) return;
    int s = ei[e];
    int d = ei[N_EDGES + e];
    int t = etype[e];
    int pos = offsets[d] + rank[e];
    elist[pos] = (s << 5) | t;
}

// ---------------- aggregate (2 waves per dst node, inline exp) ----------------
__global__ __launch_bounds__(256) void aggregate(
    const int* __restrict__ offsets, const int* __restrict__ counts,
    const int* __restrict__ elist, const float* __restrict__ a_src,
    const float* __restrict__ a_dst, const float* __restrict__ a_edge_r,
    const __half* __restrict__ xh, const float* __restrict__ bias,
    float* __restrict__ out)
{
    __shared__ float4 exsh[4][64];
    __shared__ int    ssh[4][64];
    __shared__ float4 pnum[4][64];
    __shared__ float4 pden[4][64];

    int lane = threadIdx.x & 63;
    int warp = threadIdx.x >> 6;   // 0..3
    int pair = warp >> 1;
    int half = warp & 1;
    int d = blockIdx.x * 2 + pair;

    int beg = offsets[d];
    int deg = counts[d];
    int h1 = (deg + 1) >> 1;
    int mybeg = beg + (half ? h1 : 0);
    int mydeg = half ? (deg - h1) : h1;

    float4 advec = ((const float4*)a_dst)[d];

    float n0 = 0.f, n1 = 0.f, n2 = 0.f, n3 = 0.f;
    float d0 = 0.f, d1 = 0.f, d2 = 0.f, d3 = 0.f;

    for (int base = 0; base < mydeg; base += 64) {
        int m = mydeg - base; if (m > 64) m = 64;

        float4 ev = make_float4(0.f, 0.f, 0.f, 0.f);
        int s = 0;
        if (lane < m) {
            int pk = elist[mybeg + base + lane];
            s = pk >> 5;
            int t = pk & 31;
            float4 as = ((const float4*)a_src)[s];
            float4 ae = ((const float4*)a_edge_r)[t];
            float b0 = as.x + advec.x + ae.x; b0 = b0 > 0.f ? b0 : NEG_SLOPE * b0;
            float b1 = as.y + advec.y + ae.y; b1 = b1 > 0.f ? b1 : NEG_SLOPE * b1;
            float b2 = as.z + advec.z + ae.z; b2 = b2 > 0.f ? b2 : NEG_SLOPE * b2;
            float b3 = as.w + advec.w + ae.w; b3 = b3 > 0.f ? b3 : NEG_SLOPE * b3;
            ev.x = __expf(b0); ev.y = __expf(b1);
            ev.z = __expf(b2); ev.w = __expf(b3);
        }
        d0 += ev.x; d1 += ev.y; d2 += ev.z; d3 += ev.w;
        exsh[warp][lane] = ev;   // wave-private rows; wave-synchronous RAW
        ssh[warp][lane]  = s;

        #pragma unroll 4
        for (int j = 0; j < m; ++j) {
            float4 e = exsh[warp][j];   // broadcast read (no conflict)
            int sj = ssh[warp][j];
            const __half2* __restrict__ xr =
                (const __half2*)(xh + (size_t)sj * 256 + lane * 4);
            __half2 p0 = xr[0], p1 = xr[1];
            float2 f0 = __half22float2(p0), f1 = __half22float2(p1);
            n0 = fmaf(e.x, f0.x, n0);
            n1 = fmaf(e.y, f0.y, n1);
            n2 = fmaf(e.z, f1.x, n2);
            n3 = fmaf(e.w, f1.y, n3);
        }
    }

    pnum[warp][lane] = make_float4(n0, n1, n2, n3);
    pden[warp][lane] = make_float4(d0, d1, d2, d3);
    __syncthreads();

    if (half == 0) {
        float4 on = pnum[warp + 1][lane];
        float4 od = pden[warp + 1][lane];
        n0 += on.x; n1 += on.y; n2 += on.z; n3 += on.w;
        d0 += od.x; d1 += od.y; d2 += od.z; d3 += od.w;

        #pragma unroll
        for (int msk = 32; msk >= 1; msk >>= 1) {
            d0 += __shfl_xor(d0, msk);
            d1 += __shfl_xor(d1, msk);
            d2 += __shfl_xor(d2, msk);
            d3 += __shfl_xor(d3, msk);
        }

        float r = 0.f;
        if (deg > 0)
            r = 0.25f * (n0 / d0 + n1 / d1 + n2 / d2 + n3 / d3);
        out[(size_t)d * 64 + lane] = r + bias[lane];
    }
}

extern "C" void kernel_launch(void* const* d_in, const int* in_sizes, int n_in,
                              void* d_out, int out_size, void* d_ws, size_t ws_size,
                              hipStream_t stream) {
    const float* x        = (const float*)d_in[0];
    const int*   ei       = (const int*)  d_in[1];
    const int*   etype    = (const int*)  d_in[2];
    const float* rel_emb  = (const float*)d_in[3];
    const float* W        = (const float*)d_in[4];
    const float* W_e      = (const float*)d_in[5];
    const float* att_src  = (const float*)d_in[6];
    const float* att_dst  = (const float*)d_in[7];
    const float* att_edge = (const float*)d_in[8];
    const float* bias     = (const float*)d_in[9];
    float* out = (float*)d_out;

    char* ws = (char*)d_ws;
    __half* xh      = (__half*)ws;                              // 25.6 MB
    char* p = ws + (size_t)N_NODES * 256 * 2;
    int*   counts   = (int*)p;                p += N_NODES * 4;   // zeroed
    float* a_src    = (float*)p;              p += N_NODES * 4 * 4;
    float* a_dst    = (float*)p;              p += N_NODES * 4 * 4;
    float* a_edge_r = (float*)p;              p += NREL * 4 * 4;
    int*   offsets  = (int*)p;                p += N_NODES * 4;
    int*   blocksums= (int*)p;                p += 256 * 4;
    int*   rank     = (int*)p;                p += (size_t)N_EDGES * 4;
    int*   elist    = (int*)p;                p += (size_t)N_EDGES * 4;

    hipMemsetAsync(counts, 0, N_NODES * sizeof(int), stream);
    mega_kernel<<<NXB + HIST_NB + NREL, 256, 0, stream>>>(
        x, W, att_src, att_dst, xh, a_src, a_dst,
        ei, counts, rank, rel_emb, W_e, att_edge, a_edge_r);
    scan1_kernel<<<SCAN_NB, 256, 0, stream>>>(counts, offsets, blocksums);
    scan23_kernel<<<SCAN_NB, 256, 0, stream>>>(offsets, blocksums);
    scatter_kernel<<<HIST_NB, 256, 0, stream>>>(ei, etype, offsets, rank, elist);
    aggregate<<<N_NODES / 2, 256, 0, stream>>>(offsets, counts, elist, a_src,
                                               a_dst, a_edge_r, xh, bias, out);
}